// Round 18
// baseline (258.780 us; speedup 1.0000x reference)
//
#include <hip/hip_runtime.h>

#define NEG_SLOPE 0.2f
#define CAP 64  // per-node edge bucket capacity (Poisson(16)+selfloop; P(overflow)~1e-19)
#define LOG2E 1.44269504f

typedef short bf16x8 __attribute__((ext_vector_type(8)));
typedef float f32x4 __attribute__((ext_vector_type(4)));
typedef _Float16 half4v __attribute__((ext_vector_type(4)));
typedef _Float16 half8v __attribute__((ext_vector_type(8)));

// fp32 -> bf16 round-to-nearest-even
__device__ inline short bf16_rne(float x) {
    unsigned u = __float_as_uint(x);
    unsigned r = u + 0x7FFFu + ((u >> 16) & 1u);
    return (short)(r >> 16);
}

__device__ inline float fast_exp2(float x) {
#if __has_builtin(__builtin_amdgcn_exp2f)
    return __builtin_amdgcn_exp2f(x);
#else
    return exp2f(x);
#endif
}

// ---------------- prep: W1^T bf16, W2^T fp16, bucket init (cursor=1, self-loop slot 0) -------

__global__ void k_prepw(const float* __restrict__ W1, short* __restrict__ Wt,
                        const float* __restrict__ W2, _Float16* __restrict__ W2t,
                        int* __restrict__ cursor, int* __restrict__ col, int N) {
    int r = blockIdx.x;          // 0..255 (row of W1)
    int t = threadIdx.x;         // 0..255 (col of W1)
    Wt[(size_t)t * 256 + r] = bf16_rne(W1[(size_t)r * 256 + t]);
    if (t < 32) W2t[(size_t)t * 256 + r] = (_Float16)W2[(size_t)r * 32 + t];
    int gid = blockIdx.x * 256 + threadIdx.x;
    if (gid < N) {
        cursor[gid] = 1;                 // self-loop pre-counted
        col[(size_t)gid * CAP] = gid;    // self-loop in slot 0
    }
}

// ---------------- fused GEMM1 + scatter: k-loop-paced atomics (R12-verified best) ------------
// R17: epilogue drops the as1 (a_src) dot entirely — fuse1 recomputes it in-register from
// the h1 rows it already gathers (saves 850k random as1 line fetches ~48MB fabric).
// Keeps ad1 (per-NODE, one scalar load per fuse1 wave).

__global__ __launch_bounds__(256) void k_gemm1_scatter(
        const float* __restrict__ x, const short* __restrict__ Wt,
        const float* __restrict__ a_dst,
        _Float16* __restrict__ h1, float* __restrict__ ad1, int N,
        const int* __restrict__ srcI, const int* __restrict__ dstI,
        int* __restrict__ cursor, int* __restrict__ col, int E) {
    __shared__ short Ab[64 * 40];   // [m][k], stride 40
    __shared__ short Bb[256 * 40];  // [n][k], stride 40
    const int tid = threadIdx.x;
    const int b = blockIdx.x;
    const int nGemm = gridDim.x;

    // ---- scatter slice: load 4 edges/thread now (plain loads, no atomics) ----
    const int chunk = (E + nGemm - 1) / nGemm;
    const int ss = b * chunk;
    const int se = (ss + chunk < E) ? (ss + chunk) : E;
    const int jb = ss + tid * 4;
    int4 d4 = make_int4(0, 0, 0, 0), s4 = make_int4(0, 0, 0, 0);
    int p0 = CAP, p1 = CAP, p2 = CAP, p3 = CAP;
    const bool quad = (jb + 3 < se);
    if (quad) {
        d4 = *(const int4*)(dstI + jb);
        s4 = *(const int4*)(srcI + jb);
    } else if (jb < se) {
        for (int i = jb; i < se; ++i) {
            int d = dstI[i];
            int p = atomicAdd(&cursor[d], 1);
            if (p < CAP) col[(size_t)d * CAP + p] = srcI[i];
        }
    }

    // ---- GEMM tile with paced scatter ops ----
    const int lane = tid & 63;
    const int wc = tid >> 6;             // wave index == head
    const int row0 = b * 64;
    const int m15 = lane & 15, quad4 = lane >> 4;

    f32x4 acc[4][4] = {};

    const int arow = tid >> 2;           // 0..63
    const int akseg = (tid & 3) * 8;     // 0,8,16,24

#pragma unroll
    for (int kk = 0; kk < 8; ++kk) {
        const int k0 = kk * 32;
        {
            int row = row0 + arow;
            float vals[8];
            if (row < N) {
                float4 v0 = *(const float4*)(x + (size_t)row * 256 + k0 + akseg);
                float4 v1 = *(const float4*)(x + (size_t)row * 256 + k0 + akseg + 4);
                vals[0] = v0.x; vals[1] = v0.y; vals[2] = v0.z; vals[3] = v0.w;
                vals[4] = v1.x; vals[5] = v1.y; vals[6] = v1.z; vals[7] = v1.w;
            } else {
#pragma unroll
                for (int i = 0; i < 8; ++i) vals[i] = 0.f;
            }
            short buf[8];
#pragma unroll
            for (int i = 0; i < 8; ++i) buf[i] = bf16_rne(vals[i]);
            *(bf16x8*)&Ab[arow * 40 + akseg] = *(bf16x8*)&buf[0];
        }
        {
#pragma unroll
            for (int s = 0; s < 4; ++s)
                *(bf16x8*)&Bb[tid * 40 + s * 8] =
                    *(const bf16x8*)(Wt + (size_t)tid * 256 + k0 + s * 8);
        }
        // paced scatter: even iter -> issue atomic for edge kk/2; odd -> store edge kk/2.
        if (quad) {
            const int e = kk >> 1;
            const int d = (e == 0) ? d4.x : (e == 1) ? d4.y : (e == 2) ? d4.z : d4.w;
            if ((kk & 1) == 0) {
                int pr = atomicAdd(&cursor[d], 1);
                if (e == 0) p0 = pr; else if (e == 1) p1 = pr;
                else if (e == 2) p2 = pr; else p3 = pr;
            } else {
                const int s = (e == 0) ? s4.x : (e == 1) ? s4.y : (e == 2) ? s4.z : s4.w;
                const int pr = (e == 0) ? p0 : (e == 1) ? p1 : (e == 2) ? p2 : p3;
                if (pr < CAP) col[(size_t)d * CAP + pr] = s;
            }
        }
        __syncthreads();
        bf16x8 ab[4];
#pragma unroll
        for (int mt = 0; mt < 4; ++mt)
            ab[mt] = *(const bf16x8*)&Ab[(mt * 16 + m15) * 40 + quad4 * 8];
#pragma unroll
        for (int nt = 0; nt < 4; ++nt) {
            int nn = wc * 64 + nt * 16 + m15;
            bf16x8 bb = *(const bf16x8*)&Bb[nn * 40 + quad4 * 8];
#pragma unroll
            for (int mt = 0; mt < 4; ++mt)
                acc[mt][nt] = __builtin_amdgcn_mfma_f32_16x16x32_bf16(ab[mt], bb, acc[mt][nt], 0, 0, 0);
        }
        __syncthreads();
    }
    const int head = wc;
#pragma unroll
    for (int mt = 0; mt < 4; ++mt) {
        float vd[4] = {0.f, 0.f, 0.f, 0.f};
#pragma unroll
        for (int nt = 0; nt < 4; ++nt) {
            int colg = wc * 64 + nt * 16 + m15;
            float adv = a_dst[colg];
#pragma unroll
            for (int r = 0; r < 4; ++r) {
                float accv = acc[mt][nt][r];
                int row = row0 + mt * 16 + quad4 * 4 + r;
                if (row < N) h1[(size_t)row * 256 + colg] = (_Float16)accv;
                vd[r] = fmaf(accv, adv, vd[r]);
            }
        }
#pragma unroll
        for (int r = 0; r < 4; ++r) {
#pragma unroll
            for (int mq = 1; mq < 16; mq <<= 1)
                vd[r] += __shfl_xor(vd[r], mq);
            int row = row0 + mt * 16 + quad4 * 4 + r;
            if (m15 == 0 && row < N)
                ad1[(size_t)row * 4 + head] = vd[r] * LOG2E;   // pre-scaled for exp2
        }
    }
}

// ---------------- fused gather1 + GEMM2 + alpha2 ----------
// R17: per-edge alpha_src RECOMPUTED in-register from the h1 row the wave already loads:
// lane partial dot (4 fma with a_src[4l..4l+3] held in regs) + 4-step shfl_xor reduce
// within the 16-lane head group. Eliminates 850k random as1 line fetches (~48MB fabric,
// ~23% of this kernel's FETCH). Numerics: fp16-dot err ~2e-4 on e, negligible.

__global__ __launch_bounds__(256) void k_fuse1(
        const _Float16* __restrict__ h1, const float* __restrict__ a_s1,
        const float* __restrict__ ad1, const int* __restrict__ cursor,
        const int* __restrict__ col, const float* __restrict__ b1,
        const _Float16* __restrict__ W2t,
        const float* __restrict__ a_d2, _Float16* __restrict__ z,
        float* __restrict__ ad2, int N) {
    __shared__ _Float16 W2s[32 * 264];   // [c][k], pad 8 shorts (16B) per row
    __shared__ _Float16 h2s[4 * 256];    // per-wave h2 slot
    const int tid = threadIdx.x;
    const int l = tid & 63;
    const int wave = tid >> 6;
    const int n = blockIdx.x * 4 + wave;

    for (int i8 = tid; i8 < 1024; i8 += 256) {
        int elem = i8 * 8;
        int row = elem >> 8, k = elem & 255;
        *(half8v*)&W2s[row * 264 + k] = *(const half8v*)(W2t + (size_t)row * 256 + k);
    }
    __syncthreads();
    if (n >= N) return;

    const int head = l >> 4;
    const int beg = n * CAP;
    int deg = __builtin_amdgcn_readfirstlane(cursor[n]);
    if (deg > CAP) deg = CAP;
    int colv = 0;
    if (l < deg) colv = col[beg + l];
    float adv = ad1[(size_t)n * 4 + head];
    const float4 a1v = *(const float4*)(a_s1 + 4 * l);   // a_src slice for this lane's channels

#define EDOT(HV, OUT)                                                            \
    {                                                                            \
        float t_ = fmaf((float)HV.x, a1v.x, fmaf((float)HV.y, a1v.y,             \
                   fmaf((float)HV.z, a1v.z, (float)HV.w * a1v.w)));              \
        t_ += __shfl_xor(t_, 1);                                                 \
        t_ += __shfl_xor(t_, 2);                                                 \
        t_ += __shfl_xor(t_, 4);                                                 \
        t_ += __shfl_xor(t_, 8);                                                 \
        OUT = t_;                                                                \
    }

    f32x4 a0 = {}, a1a = {}, a2 = {}, a3 = {};
    float s0 = 0.f, s1 = 0.f, s2 = 0.f, s3 = 0.f;
    int j = 0;
    for (; j + 3 < deg; j += 4) {
        int c0 = __builtin_amdgcn_readlane(colv, j);
        int c1 = __builtin_amdgcn_readlane(colv, j + 1);
        int c2 = __builtin_amdgcn_readlane(colv, j + 2);
        int c3 = __builtin_amdgcn_readlane(colv, j + 3);
        half4v h0 = *((const half4v*)(h1 + (size_t)c0 * 256) + l);
        half4v hv1 = *((const half4v*)(h1 + (size_t)c1 * 256) + l);
        half4v h2 = *((const half4v*)(h1 + (size_t)c2 * 256) + l);
        half4v h3 = *((const half4v*)(h1 + (size_t)c3 * 256) + l);
        float d0, d1, d2, d3;
        EDOT(h0, d0) EDOT(hv1, d1) EDOT(h2, d2) EDOT(h3, d3)
        float e0 = fmaf(d0, LOG2E, adv), e1 = fmaf(d1, LOG2E, adv);
        float e2 = fmaf(d2, LOG2E, adv), e3 = fmaf(d3, LOG2E, adv);
        e0 = fmaxf(e0, NEG_SLOPE * e0); e1 = fmaxf(e1, NEG_SLOPE * e1);
        e2 = fmaxf(e2, NEG_SLOPE * e2); e3 = fmaxf(e3, NEG_SLOPE * e3);
        float p0 = fast_exp2(e0), p1 = fast_exp2(e1);
        float p2 = fast_exp2(e2), p3 = fast_exp2(e3);
        s0 += p0; s1 += p1; s2 += p2; s3 += p3;
        a0 += __builtin_convertvector(h0, f32x4) * p0;
        a1a += __builtin_convertvector(hv1, f32x4) * p1;
        a2 += __builtin_convertvector(h2, f32x4) * p2;
        a3 += __builtin_convertvector(h3, f32x4) * p3;
    }
    for (; j < deg; ++j) {
        int c0 = __builtin_amdgcn_readlane(colv, j);
        half4v h0 = *((const half4v*)(h1 + (size_t)c0 * 256) + l);
        float d0;
        EDOT(h0, d0)
        float e0 = fmaf(d0, LOG2E, adv);
        e0 = fmaxf(e0, NEG_SLOPE * e0);
        float p0 = fast_exp2(e0);
        s0 += p0;
        a0 += __builtin_convertvector(h0, f32x4) * p0;
    }
#undef EDOT
    f32x4 at = (a0 + a1a) + (a2 + a3);
    float iv = 1.f / ((s0 + s1) + (s2 + s3) + 1e-16f);
    float4 bb = *(const float4*)(b1 + l * 4);
    float4 v;
    v.x = at[0] * iv + bb.x;
    v.y = at[1] * iv + bb.y;
    v.z = at[2] * iv + bb.z;
    v.w = at[3] * iv + bb.w;
    v.x = (v.x > 0.f) ? v.x : (__expf(v.x) - 1.f);
    v.y = (v.y > 0.f) ? v.y : (__expf(v.y) - 1.f);
    v.z = (v.z > 0.f) ? v.z : (__expf(v.z) - 1.f);
    v.w = (v.w > 0.f) ? v.w : (__expf(v.w) - 1.f);
    half4v hv;
    hv.x = (_Float16)v.x; hv.y = (_Float16)v.y; hv.z = (_Float16)v.z; hv.w = (_Float16)v.w;
    *((half4v*)(h2s + wave * 256) + l) = hv;   // same-wave LDS, no barrier needed

    // GEMM2 row: lane l -> channel c = l&31, k-half kh = (l>>5)*128
    int c = l & 31;
    int kh = (l >> 5) * 128;
    const _Float16* hrow = h2s + wave * 256 + kh;
    const _Float16* wrow = W2s + c * 264 + kh;
    float accz = 0.f;
#pragma unroll
    for (int k = 0; k < 128; k += 8) {
        half8v hz = *(const half8v*)(hrow + k);
        half8v wz = *(const half8v*)(wrow + k);
#if __has_builtin(__builtin_amdgcn_fdot2)
        accz = __builtin_amdgcn_fdot2(__builtin_shufflevector(hz, hz, 0, 1),
                                      __builtin_shufflevector(wz, wz, 0, 1), accz, false);
        accz = __builtin_amdgcn_fdot2(__builtin_shufflevector(hz, hz, 2, 3),
                                      __builtin_shufflevector(wz, wz, 2, 3), accz, false);
        accz = __builtin_amdgcn_fdot2(__builtin_shufflevector(hz, hz, 4, 5),
                                      __builtin_shufflevector(wz, wz, 4, 5), accz, false);
        accz = __builtin_amdgcn_fdot2(__builtin_shufflevector(hz, hz, 6, 7),
                                      __builtin_shufflevector(wz, wz, 6, 7), accz, false);
#else
        accz = fmaf((float)hz[0], (float)wz[0], accz);
        accz = fmaf((float)hz[1], (float)wz[1], accz);
        accz = fmaf((float)hz[2], (float)wz[2], accz);
        accz = fmaf((float)hz[3], (float)wz[3], accz);
        accz = fmaf((float)hz[4], (float)wz[4], accz);
        accz = fmaf((float)hz[5], (float)wz[5], accz);
        accz = fmaf((float)hz[6], (float)wz[6], accz);
        accz = fmaf((float)hz[7], (float)wz[7], accz);
#endif
    }
    accz += __shfl_xor(accz, 32);
    float zd = accz * a_d2[c];
#pragma unroll
    for (int mq = 1; mq < 32; mq <<= 1)
        zd += __shfl_xor(zd, mq);
    if (l < 32) z[(size_t)n * 32 + c] = (_Float16)accz;
    if (l == 0) ad2[n] = zd * LOG2E;   // pre-scaled for exp2
}

// ---------------- gather2: burst-MLP + in-register alpha_src recompute (R17) -----------------
// as2[src] recomputed from the z row already in registers: 4-fma partial with a_s2 slice
// + 3-step shfl_xor reduce within the 8-lane group. Eliminates 850k random as2 line
// fetches (~half this kernel's fabric traffic).

__global__ void k_gather2(const _Float16* __restrict__ z, const float* __restrict__ a_s2,
                          const float* __restrict__ ad2, const int* __restrict__ cursor,
                          const int* __restrict__ col, const float* __restrict__ b2,
                          float* __restrict__ out, int N) {
    int n = blockIdx.x * 4 + (threadIdx.x >> 6);
    if (n >= N) return;
    int l = threadIdx.x & 63;
    int eo = l >> 3;
    int cg = l & 7;
    int beg = n * CAP;
    int deg = __builtin_amdgcn_readfirstlane(cursor[n]);
    if (deg > CAP) deg = CAP;
    int colv = 0;
    if (l < deg) colv = col[beg + l];
    float adn = ad2[n];
    const float4 a2v = *(const float4*)(a_s2 + 4 * cg);   // a_s2 slice for this lane's channels

    const int nst = (deg + 7) >> 3;   // 1..8 (deg>=1 via self-loop)

    half4v zv_[8];
#pragma unroll
    for (int t = 0; t < 8; ++t) {
        if (t < nst) {
            int idx = t * 8 + eo;
            int sidx = (idx < deg) ? idx : 0;    // lane-0 colv is always valid (deg>=1)
            int src = __shfl(colv, sidx);
            zv_[t] = *((const half4v*)(z + (size_t)src * 32) + cg);
        }
    }

    f32x4 acc = {};
    float s = 0.f;
#pragma unroll
    for (int t = 0; t < 8; ++t) {
        if (t < nst) {
            int idx = t * 8 + eo;
            float d_ = fmaf((float)zv_[t].x, a2v.x, fmaf((float)zv_[t].y, a2v.y,
                       fmaf((float)zv_[t].z, a2v.z, (float)zv_[t].w * a2v.w)));
            d_ += __shfl_xor(d_, 1);
            d_ += __shfl_xor(d_, 2);
            d_ += __shfl_xor(d_, 4);
            float e = fmaf(d_, LOG2E, adn);
            e = fmaxf(e, NEG_SLOPE * e);
            float p = (idx < deg) ? fast_exp2(e) : 0.f;
            s += p;
            acc += __builtin_convertvector(zv_[t], f32x4) * p;
        }
    }

    float ax = acc[0], ay = acc[1], az = acc[2], aw = acc[3];
#pragma unroll
    for (int mq = 8; mq < 64; mq <<= 1) {
        ax += __shfl_xor(ax, mq);
        ay += __shfl_xor(ay, mq);
        az += __shfl_xor(az, mq);
        aw += __shfl_xor(aw, mq);
        s += __shfl_xor(s, mq);
    }
    if (eo == 0) {
        float iv = 1.f / (s + 1e-16f);
        float4 bb = *(const float4*)(b2 + cg * 4);
        float4 v;
        v.x = ax * iv + bb.x;
        v.y = ay * iv + bb.y;
        v.z = az * iv + bb.z;
        v.w = aw * iv + bb.w;
        *(float4*)(out + (size_t)n * 32 + cg * 4) = v;
    }
}

// ---------------- launch ----------------

extern "C" void kernel_launch(void* const* d_in, const int* in_sizes, int n_in,
                              void* d_out, int out_size, void* d_ws, size_t ws_size,
                              hipStream_t stream) {
    const float* x    = (const float*)d_in[0];
    const int*   ei   = (const int*)d_in[1];
    const float* W1   = (const float*)d_in[2];
    const float* a_s1 = (const float*)d_in[3];
    const float* a_d1 = (const float*)d_in[4];
    const float* b1   = (const float*)d_in[5];
    const float* W2   = (const float*)d_in[6];
    const float* a_s2 = (const float*)d_in[7];
    const float* a_d2 = (const float*)d_in[8];
    const float* b2   = (const float*)d_in[9];
    float* out = (float*)d_out;

    const int N = in_sizes[0] / 256;
    const int E = in_sizes[1] / 2;
    const int* srcIdx = ei;
    const int* dstIdx = ei + E;

    char* ws = (char*)d_ws;
    size_t off = 0;
    auto alloc = [&](size_t bytes) {
        void* p = ws + off;
        off += (bytes + 255) & ~(size_t)255;
        return p;
    };
    _Float16* h1   = (_Float16*)alloc((size_t)N * 256 * 2);  // fp16 gather table (layer1)
    _Float16* z    = (_Float16*)alloc((size_t)N * 32 * 2);   // fp16 gather table (layer2)
    float* ad1    = (float*)alloc((size_t)N * 16);
    float* ad2    = (float*)alloc((size_t)N * 4);
    short* Wt     = (short*)alloc((size_t)256 * 256 * 2);    // W1^T bf16
    _Float16* W2t = (_Float16*)alloc((size_t)32 * 256 * 2);  // W2^T fp16
    int*   cursor = (int*)alloc((size_t)N * 4);
    int*   col    = (int*)alloc((size_t)N * CAP * 4);        // fixed-capacity buckets

    // prep (weights + bucket init)
    k_prepw<<<256, 256, 0, stream>>>(W1, Wt, W2, W2t, cursor, col, N);

    // fused layer-1 GEMM + edge scatter (R12-verified k-loop-paced atomics)
    const int nGemm = (N + 63) / 64;
    k_gemm1_scatter<<<nGemm, 256, 0, stream>>>(x, Wt, a_d1, h1, ad1, N,
                                               srcIdx, dstIdx, cursor, col, E);

    // fused: gather1-softmax (in-register alpha) + ELU + GEMM2 + alpha2
    k_fuse1<<<(N + 3) / 4, 256, 0, stream>>>(h1, a_s1, ad1, cursor, col, b1, W2t,
                                             a_d2, z, ad2, N);

    // layer 2 gather (burst-MLP + in-register alpha)
    k_gather2<<<(N + 3) / 4, 256, 0, stream>>>(z, a_s2, ad2, cursor, col, b2, out, N);
}

// Round 19
// 245.978 us; speedup vs baseline: 1.0520x; 1.0520x over previous
//
#include <hip/hip_runtime.h>

#define NEG_SLOPE 0.2f
#define CAP 64  // per-node edge bucket capacity (Poisson(16)+selfloop; P(overflow)~1e-19)
#define LOG2E 1.44269504f

typedef short bf16x8 __attribute__((ext_vector_type(8)));
typedef float f32x4 __attribute__((ext_vector_type(4)));
typedef _Float16 half4v __attribute__((ext_vector_type(4)));
typedef _Float16 half8v __attribute__((ext_vector_type(8)));

// fp32 -> bf16 round-to-nearest-even
__device__ inline short bf16_rne(float x) {
    unsigned u = __float_as_uint(x);
    unsigned r = u + 0x7FFFu + ((u >> 16) & 1u);
    return (short)(r >> 16);
}

__device__ inline float fast_exp2(float x) {
#if __has_builtin(__builtin_amdgcn_exp2f)
    return __builtin_amdgcn_exp2f(x);
#else
    return exp2f(x);
#endif
}

// ---------------- prep: W1^T bf16, W2^T fp16, bucket init (cursor=1, self-loop slot 0) -------
// Coalesced-read transpose (R10 form).

__global__ void k_prepw(const float* __restrict__ W1, short* __restrict__ Wt,
                        const float* __restrict__ W2, _Float16* __restrict__ W2t,
                        int* __restrict__ cursor, int* __restrict__ col, int N) {
    int r = blockIdx.x;          // 0..255 (row of W1)
    int t = threadIdx.x;         // 0..255 (col of W1)
    Wt[(size_t)t * 256 + r] = bf16_rne(W1[(size_t)r * 256 + t]);
    if (t < 32) W2t[(size_t)t * 256 + r] = (_Float16)W2[(size_t)r * 32 + t];
    int gid = blockIdx.x * 256 + threadIdx.x;
    if (gid < N) {
        cursor[gid] = 1;                 // self-loop pre-counted
        col[(size_t)gid * CAP] = gid;    // self-loop in slot 0
    }
}

// ---------------- fused GEMM1 + scatter: k-loop-paced atomics (R12/R16-verified best) --------

__global__ __launch_bounds__(256) void k_gemm1_scatter(
        const float* __restrict__ x, const short* __restrict__ Wt,
        const float* __restrict__ a_src, const float* __restrict__ a_dst,
        _Float16* __restrict__ h1, float* __restrict__ as1, float* __restrict__ ad1, int N,
        const int* __restrict__ srcI, const int* __restrict__ dstI,
        int* __restrict__ cursor, int* __restrict__ col, int E) {
    __shared__ short Ab[64 * 40];   // [m][k], stride 40
    __shared__ short Bb[256 * 40];  // [n][k], stride 40
    const int tid = threadIdx.x;
    const int b = blockIdx.x;
    const int nGemm = gridDim.x;

    // ---- scatter slice: load 4 edges/thread now (plain loads, no atomics) ----
    const int chunk = (E + nGemm - 1) / nGemm;
    const int ss = b * chunk;
    const int se = (ss + chunk < E) ? (ss + chunk) : E;
    const int jb = ss + tid * 4;
    int4 d4 = make_int4(0, 0, 0, 0), s4 = make_int4(0, 0, 0, 0);
    int p0 = CAP, p1 = CAP, p2 = CAP, p3 = CAP;
    const bool quad = (jb + 3 < se);
    if (quad) {
        d4 = *(const int4*)(dstI + jb);
        s4 = *(const int4*)(srcI + jb);
    } else if (jb < se) {
        for (int i = jb; i < se; ++i) {
            int d = dstI[i];
            int p = atomicAdd(&cursor[d], 1);
            if (p < CAP) col[(size_t)d * CAP + p] = srcI[i];
        }
    }

    // ---- GEMM tile with paced scatter ops ----
    const int lane = tid & 63;
    const int wc = tid >> 6;             // wave index == head
    const int row0 = b * 64;
    const int m15 = lane & 15, quad4 = lane >> 4;

    f32x4 acc[4][4] = {};

    const int arow = tid >> 2;           // 0..63
    const int akseg = (tid & 3) * 8;     // 0,8,16,24

#pragma unroll
    for (int kk = 0; kk < 8; ++kk) {
        const int k0 = kk * 32;
        {
            int row = row0 + arow;
            float vals[8];
            if (row < N) {
                float4 v0 = *(const float4*)(x + (size_t)row * 256 + k0 + akseg);
                float4 v1 = *(const float4*)(x + (size_t)row * 256 + k0 + akseg + 4);
                vals[0] = v0.x; vals[1] = v0.y; vals[2] = v0.z; vals[3] = v0.w;
                vals[4] = v1.x; vals[5] = v1.y; vals[6] = v1.z; vals[7] = v1.w;
            } else {
#pragma unroll
                for (int i = 0; i < 8; ++i) vals[i] = 0.f;
            }
            short buf[8];
#pragma unroll
            for (int i = 0; i < 8; ++i) buf[i] = bf16_rne(vals[i]);
            *(bf16x8*)&Ab[arow * 40 + akseg] = *(bf16x8*)&buf[0];
        }
        {
#pragma unroll
            for (int s = 0; s < 4; ++s)
                *(bf16x8*)&Bb[tid * 40 + s * 8] =
                    *(const bf16x8*)(Wt + (size_t)tid * 256 + k0 + s * 8);
        }
        // paced scatter: even iter -> issue atomic for edge kk/2; odd -> store edge kk/2.
        if (quad) {
            const int e = kk >> 1;
            const int d = (e == 0) ? d4.x : (e == 1) ? d4.y : (e == 2) ? d4.z : d4.w;
            if ((kk & 1) == 0) {
                int pr = atomicAdd(&cursor[d], 1);
                if (e == 0) p0 = pr; else if (e == 1) p1 = pr;
                else if (e == 2) p2 = pr; else p3 = pr;
            } else {
                const int s = (e == 0) ? s4.x : (e == 1) ? s4.y : (e == 2) ? s4.z : s4.w;
                const int pr = (e == 0) ? p0 : (e == 1) ? p1 : (e == 2) ? p2 : p3;
                if (pr < CAP) col[(size_t)d * CAP + pr] = s;
            }
        }
        __syncthreads();
        bf16x8 ab[4];
#pragma unroll
        for (int mt = 0; mt < 4; ++mt)
            ab[mt] = *(const bf16x8*)&Ab[(mt * 16 + m15) * 40 + quad4 * 8];
#pragma unroll
        for (int nt = 0; nt < 4; ++nt) {
            int nn = wc * 64 + nt * 16 + m15;
            bf16x8 bb = *(const bf16x8*)&Bb[nn * 40 + quad4 * 8];
#pragma unroll
            for (int mt = 0; mt < 4; ++mt)
                acc[mt][nt] = __builtin_amdgcn_mfma_f32_16x16x32_bf16(ab[mt], bb, acc[mt][nt], 0, 0, 0);
        }
        __syncthreads();
    }
    const int head = wc;
#pragma unroll
    for (int mt = 0; mt < 4; ++mt) {
        float va[4] = {0.f, 0.f, 0.f, 0.f};
        float vd[4] = {0.f, 0.f, 0.f, 0.f};
#pragma unroll
        for (int nt = 0; nt < 4; ++nt) {
            int colg = wc * 64 + nt * 16 + m15;
            float asv = a_src[colg];
            float adv = a_dst[colg];
#pragma unroll
            for (int r = 0; r < 4; ++r) {
                float accv = acc[mt][nt][r];
                int row = row0 + mt * 16 + quad4 * 4 + r;
                if (row < N) h1[(size_t)row * 256 + colg] = (_Float16)accv;
                va[r] = fmaf(accv, asv, va[r]);
                vd[r] = fmaf(accv, adv, vd[r]);
            }
        }
#pragma unroll
        for (int r = 0; r < 4; ++r) {
#pragma unroll
            for (int mq = 1; mq < 16; mq <<= 1) {
                va[r] += __shfl_xor(va[r], mq);
                vd[r] += __shfl_xor(vd[r], mq);
            }
            int row = row0 + mt * 16 + quad4 * 4 + r;
            if (m15 == 0 && row < N) {
                as1[(size_t)row * 4 + head] = va[r] * LOG2E;   // pre-scaled for exp2
                ad1[(size_t)row * 4 + head] = vd[r] * LOG2E;
            }
        }
    }
}

// ---------------- fused gather1 + GEMM2 + alpha2 (R1-verified inner loop; R18 proved
// in-loop cross-lane shfls regress — keep the as1-load form). ----------

__global__ __launch_bounds__(256) void k_fuse1(
        const _Float16* __restrict__ h1, const float* __restrict__ as1,
        const float* __restrict__ ad1, const int* __restrict__ cursor,
        const int* __restrict__ col, const float* __restrict__ b1,
        const _Float16* __restrict__ W2t, const float* __restrict__ a_s2,
        const float* __restrict__ a_d2, _Float16* __restrict__ z,
        float* __restrict__ as2, float* __restrict__ ad2, int N) {
    __shared__ _Float16 W2s[32 * 264];   // [c][k], pad 8 shorts (16B) per row
    __shared__ _Float16 h2s[4 * 256];    // per-wave h2 slot
    const int tid = threadIdx.x;
    const int l = tid & 63;
    const int wave = tid >> 6;
    const int n = blockIdx.x * 4 + wave;

    for (int i8 = tid; i8 < 1024; i8 += 256) {
        int elem = i8 * 8;
        int row = elem >> 8, k = elem & 255;
        *(half8v*)&W2s[row * 264 + k] = *(const half8v*)(W2t + (size_t)row * 256 + k);
    }
    __syncthreads();
    if (n >= N) return;

    const int head = l >> 4;
    const int beg = n * CAP;
    int deg = __builtin_amdgcn_readfirstlane(cursor[n]);
    if (deg > CAP) deg = CAP;
    int colv = 0;
    if (l < deg) colv = col[beg + l];
    float adv = ad1[(size_t)n * 4 + head];

    f32x4 a0 = {}, a1 = {}, a2 = {}, a3 = {};
    float s0 = 0.f, s1 = 0.f, s2 = 0.f, s3 = 0.f;
    int j = 0;
    for (; j + 3 < deg; j += 4) {
        int c0 = __builtin_amdgcn_readlane(colv, j);
        int c1 = __builtin_amdgcn_readlane(colv, j + 1);
        int c2 = __builtin_amdgcn_readlane(colv, j + 2);
        int c3 = __builtin_amdgcn_readlane(colv, j + 3);
        float e0 = as1[(size_t)c0 * 4 + head] + adv;
        float e1 = as1[(size_t)c1 * 4 + head] + adv;
        float e2 = as1[(size_t)c2 * 4 + head] + adv;
        float e3 = as1[(size_t)c3 * 4 + head] + adv;
        e0 = fmaxf(e0, NEG_SLOPE * e0); e1 = fmaxf(e1, NEG_SLOPE * e1);
        e2 = fmaxf(e2, NEG_SLOPE * e2); e3 = fmaxf(e3, NEG_SLOPE * e3);
        float p0 = fast_exp2(e0), p1 = fast_exp2(e1);
        float p2 = fast_exp2(e2), p3 = fast_exp2(e3);
        half4v h0 = *((const half4v*)(h1 + (size_t)c0 * 256) + l);
        half4v hv1 = *((const half4v*)(h1 + (size_t)c1 * 256) + l);
        half4v h2 = *((const half4v*)(h1 + (size_t)c2 * 256) + l);
        half4v h3 = *((const half4v*)(h1 + (size_t)c3 * 256) + l);
        s0 += p0; s1 += p1; s2 += p2; s3 += p3;
        a0 += __builtin_convertvector(h0, f32x4) * p0;
        a1 += __builtin_convertvector(hv1, f32x4) * p1;
        a2 += __builtin_convertvector(h2, f32x4) * p2;
        a3 += __builtin_convertvector(h3, f32x4) * p3;
    }
    for (; j < deg; ++j) {
        int c0 = __builtin_amdgcn_readlane(colv, j);
        float e0 = as1[(size_t)c0 * 4 + head] + adv;
        e0 = fmaxf(e0, NEG_SLOPE * e0);
        float p0 = fast_exp2(e0);
        half4v h0 = *((const half4v*)(h1 + (size_t)c0 * 256) + l);
        s0 += p0;
        a0 += __builtin_convertvector(h0, f32x4) * p0;
    }
    f32x4 at = (a0 + a1) + (a2 + a3);
    float iv = 1.f / ((s0 + s1) + (s2 + s3) + 1e-16f);
    float4 bb = *(const float4*)(b1 + l * 4);
    float4 v;
    v.x = at[0] * iv + bb.x;
    v.y = at[1] * iv + bb.y;
    v.z = at[2] * iv + bb.z;
    v.w = at[3] * iv + bb.w;
    v.x = (v.x > 0.f) ? v.x : (__expf(v.x) - 1.f);
    v.y = (v.y > 0.f) ? v.y : (__expf(v.y) - 1.f);
    v.z = (v.z > 0.f) ? v.z : (__expf(v.z) - 1.f);
    v.w = (v.w > 0.f) ? v.w : (__expf(v.w) - 1.f);
    half4v hv;
    hv.x = (_Float16)v.x; hv.y = (_Float16)v.y; hv.z = (_Float16)v.z; hv.w = (_Float16)v.w;
    *((half4v*)(h2s + wave * 256) + l) = hv;   // same-wave LDS, no barrier needed

    // GEMM2 row: lane l -> channel c = l&31, k-half kh = (l>>5)*128
    int c = l & 31;
    int kh = (l >> 5) * 128;
    const _Float16* hrow = h2s + wave * 256 + kh;
    const _Float16* wrow = W2s + c * 264 + kh;
    float accz = 0.f;
#pragma unroll
    for (int k = 0; k < 128; k += 8) {
        half8v hz = *(const half8v*)(hrow + k);
        half8v wz = *(const half8v*)(wrow + k);
#if __has_builtin(__builtin_amdgcn_fdot2)
        accz = __builtin_amdgcn_fdot2(__builtin_shufflevector(hz, hz, 0, 1),
                                      __builtin_shufflevector(wz, wz, 0, 1), accz, false);
        accz = __builtin_amdgcn_fdot2(__builtin_shufflevector(hz, hz, 2, 3),
                                      __builtin_shufflevector(wz, wz, 2, 3), accz, false);
        accz = __builtin_amdgcn_fdot2(__builtin_shufflevector(hz, hz, 4, 5),
                                      __builtin_shufflevector(wz, wz, 4, 5), accz, false);
        accz = __builtin_amdgcn_fdot2(__builtin_shufflevector(hz, hz, 6, 7),
                                      __builtin_shufflevector(wz, wz, 6, 7), accz, false);
#else
        accz = fmaf((float)hz[0], (float)wz[0], accz);
        accz = fmaf((float)hz[1], (float)wz[1], accz);
        accz = fmaf((float)hz[2], (float)wz[2], accz);
        accz = fmaf((float)hz[3], (float)wz[3], accz);
        accz = fmaf((float)hz[4], (float)wz[4], accz);
        accz = fmaf((float)hz[5], (float)wz[5], accz);
        accz = fmaf((float)hz[6], (float)wz[6], accz);
        accz = fmaf((float)hz[7], (float)wz[7], accz);
#endif
    }
    accz += __shfl_xor(accz, 32);
    float za = accz * a_s2[c];
    float zd = accz * a_d2[c];
#pragma unroll
    for (int mq = 1; mq < 32; mq <<= 1) {
        za += __shfl_xor(za, mq);
        zd += __shfl_xor(zd, mq);
    }
    if (l < 32) z[(size_t)n * 32 + c] = (_Float16)accz;
    if (l == 0) {
        as2[n] = za * LOG2E;   // pre-scaled for exp2
        ad2[n] = zd * LOG2E;
    }
}

// ---------------- gather2: DUAL-NODE waves (R19) ---------------------------------------------
// 2 nodes per wave (32 lanes each: 8 edge slots x 4 channel-groups, half8v 16B/lane so
// 4 lanes cover a 64B z row). Halves wave count (50k->25k), doubles in-flight loads per
// wave, amortizes per-wave fixed costs (colv round, reduce, write) over 2 nodes. Burst
// structure (R16-proven) retained: all <=8 iterations' loads issued before consumption.

__global__ void k_gather2(const _Float16* __restrict__ z, const float* __restrict__ as2,
                          const float* __restrict__ ad2, const int* __restrict__ cursor,
                          const int* __restrict__ col, const float* __restrict__ b2,
                          float* __restrict__ out, int N) {
    const int tid = threadIdx.x;
    const int l = tid & 63;
    const int wave = tid >> 6;
    const int half = l >> 5;          // which node of the pair
    const int sub = l & 31;           // lane within the node's 32-lane group
    const int n = blockIdx.x * 8 + wave * 2 + half;
    if (n >= N) return;

    const int eo = sub >> 2;          // edge slot 0..7
    const int cg = sub & 3;           // channel group 0..3 (8 halves each)
    const int beg = n * CAP;
    int deg = cursor[n];              // uniform within 32-lane group (broadcast load)
    if (deg > CAP) deg = CAP;
    // bucket slots 0..31 in colv; 32..63 (rare, P(deg>32)~1e-4) in colv2
    int colv = 0, colv2 = 0;
    if (sub < deg) colv = col[beg + sub];
    if (deg > 32 && sub + 32 < deg) colv2 = col[beg + 32 + sub];
    float adn = ad2[n];

    const int nst = (deg + 7) >> 3;   // 1..8 (deg>=1 via self-loop)
    const int base = half * 32;

    float av_[8];
    half8v zv_[8];
#pragma unroll
    for (int t = 0; t < 8; ++t) {
        if (t < nst) {
            int idx = t * 8 + eo;
            int sidx = (idx < deg) ? idx : 0;    // slot 0 always valid (self-loop)
            int src = (sidx < 32) ? __shfl(colv, base + sidx)
                                  : __shfl(colv2, base + (sidx - 32));
            av_[t] = as2[src];
            zv_[t] = *((const half8v*)(z + (size_t)src * 32) + cg);
        }
    }

    f32x4 accL = {}, accH = {};
    float s = 0.f;
#pragma unroll
    for (int t = 0; t < 8; ++t) {
        if (t < nst) {
            int idx = t * 8 + eo;
            float e = av_[t] + adn;
            e = fmaxf(e, NEG_SLOPE * e);
            float p = (idx < deg) ? fast_exp2(e) : 0.f;
            s += p;
            half4v lo = __builtin_shufflevector(zv_[t], zv_[t], 0, 1, 2, 3);
            half4v hi = __builtin_shufflevector(zv_[t], zv_[t], 4, 5, 6, 7);
            accL += __builtin_convertvector(lo, f32x4) * p;
            accH += __builtin_convertvector(hi, f32x4) * p;
        }
    }

    // reduce across edge slots (masks 4/8/16 stay within the 32-lane half)
#pragma unroll
    for (int mq = 4; mq < 32; mq <<= 1) {
        accL[0] += __shfl_xor(accL[0], mq);
        accL[1] += __shfl_xor(accL[1], mq);
        accL[2] += __shfl_xor(accL[2], mq);
        accL[3] += __shfl_xor(accL[3], mq);
        accH[0] += __shfl_xor(accH[0], mq);
        accH[1] += __shfl_xor(accH[1], mq);
        accH[2] += __shfl_xor(accH[2], mq);
        accH[3] += __shfl_xor(accH[3], mq);
        s += __shfl_xor(s, mq);
    }
    if (eo == 0) {
        float iv = 1.f / (s + 1e-16f);
        const float* bp = b2 + cg * 8;
        float4 bl = *(const float4*)(bp);
        float4 bh = *(const float4*)(bp + 4);
        float4 vl, vh;
        vl.x = accL[0] * iv + bl.x; vl.y = accL[1] * iv + bl.y;
        vl.z = accL[2] * iv + bl.z; vl.w = accL[3] * iv + bl.w;
        vh.x = accH[0] * iv + bh.x; vh.y = accH[1] * iv + bh.y;
        vh.z = accH[2] * iv + bh.z; vh.w = accH[3] * iv + bh.w;
        float* op = out + (size_t)n * 32 + cg * 8;
        *(float4*)(op) = vl;
        *(float4*)(op + 4) = vh;
    }
}

// ---------------- launch ----------------

extern "C" void kernel_launch(void* const* d_in, const int* in_sizes, int n_in,
                              void* d_out, int out_size, void* d_ws, size_t ws_size,
                              hipStream_t stream) {
    const float* x    = (const float*)d_in[0];
    const int*   ei   = (const int*)d_in[1];
    const float* W1   = (const float*)d_in[2];
    const float* a_s1 = (const float*)d_in[3];
    const float* a_d1 = (const float*)d_in[4];
    const float* b1   = (const float*)d_in[5];
    const float* W2   = (const float*)d_in[6];
    const float* a_s2 = (const float*)d_in[7];
    const float* a_d2 = (const float*)d_in[8];
    const float* b2   = (const float*)d_in[9];
    float* out = (float*)d_out;

    const int N = in_sizes[0] / 256;
    const int E = in_sizes[1] / 2;
    const int* srcIdx = ei;
    const int* dstIdx = ei + E;

    char* ws = (char*)d_ws;
    size_t off = 0;
    auto alloc = [&](size_t bytes) {
        void* p = ws + off;
        off += (bytes + 255) & ~(size_t)255;
        return p;
    };
    _Float16* h1   = (_Float16*)alloc((size_t)N * 256 * 2);  // fp16 gather table (layer1)
    _Float16* z    = (_Float16*)alloc((size_t)N * 32 * 2);   // fp16 gather table (layer2)
    float* as1    = (float*)alloc((size_t)N * 16);
    float* ad1    = (float*)alloc((size_t)N * 16);
    float* as2    = (float*)alloc((size_t)N * 4);
    float* ad2    = (float*)alloc((size_t)N * 4);
    short* Wt     = (short*)alloc((size_t)256 * 256 * 2);    // W1^T bf16
    _Float16* W2t = (_Float16*)alloc((size_t)32 * 256 * 2);  // W2^T fp16
    int*   cursor = (int*)alloc((size_t)N * 4);
    int*   col    = (int*)alloc((size_t)N * CAP * 4);        // fixed-capacity buckets

    // prep (weights + bucket init)
    k_prepw<<<256, 256, 0, stream>>>(W1, Wt, W2, W2t, cursor, col, N);

    // fused layer-1 GEMM + edge scatter (R12-verified k-loop-paced atomics)
    const int nGemm = (N + 63) / 64;
    k_gemm1_scatter<<<nGemm, 256, 0, stream>>>(x, Wt, a_s1, a_d1, h1, as1, ad1, N,
                                               srcIdx, dstIdx, cursor, col, E);

    // fused: gather1-softmax + ELU + GEMM2 + alpha2
    k_fuse1<<<(N + 3) / 4, 256, 0, stream>>>(h1, as1, ad1, cursor, col, b1, W2t,
                                             a_s2, a_d2, z, as2, ad2, N);

    // layer 2 gather (dual-node waves)
    k_gather2<<<(N + 7) / 8, 256, 0, stream>>>(z, as2, ad2, cursor, col, b2, out, N);
}